// Round 2
// baseline (62.893 us; speedup 1.0000x reference)
//
#include <hip/hip_runtime.h>
#include <hip/hip_cooperative_groups.h>
#include <math.h>

namespace cg = cooperative_groups;

#define H    1024
#define D2   2048   // input width of both big GEMVs

__device__ __forceinline__ float sigmoidf_(float x) {
    return 1.0f / (1.0f + expf(-x));
}

__device__ __forceinline__ float wave_sum(float v) {
#pragma unroll
    for (int off = 32; off >= 1; off >>= 1)
        v += __shfl_xor(v, off, 64);
    return v;
}

// One cooperative kernel, 256 blocks x 256 threads (4 waves/block).
// Phase 1: block b computes h_map[b*4 .. b*4+3] (one wave per row, 3 gate-dots
//          each) and h_pts[b*4 .. b*4+3] (4 lanes, trivial 4-wide dots).
//          Block 0 initializes out = fc_b.
// Prefetch: each wave loads its W_ih_1 rows (i,g,o) into registers — these do
//          NOT depend on fin, so they overlap the grid-sync drain.
// Phase 2: after grid.sync(), read fin (8KB, L2-hot), FMA vs register weights,
//          activations, then per-block LDS reduce + atomicAdd into out.
__global__ __launch_bounds__(256) void k_fused(
    const float* __restrict__ x,      // map [2048]
    const float* __restrict__ Wm,     // W_ih_map [4096][2048]
    const float* __restrict__ bm_i,
    const float* __restrict__ bm_h,
    const float* __restrict__ Wp,     // W_ih_pts [4096][4]
    const float* __restrict__ bp_i,
    const float* __restrict__ bp_h,
    const float* __restrict__ W1,     // W_ih_1 [4096][2048]
    const float* __restrict__ b1_i,
    const float* __restrict__ b1_h,
    const float* __restrict__ goal,   // [2]
    const float* __restrict__ cur,    // [2]
    const float* __restrict__ fcw,    // [2][1024]
    const float* __restrict__ fcb,    // [2]
    float* __restrict__ fin,          // ws: [0..1023]=h_map, [1024..2047]=h_pts
    float* __restrict__ out)          // [2]
{
    const int b    = blockIdx.x;
    const int wave = threadIdx.x >> 6;
    const int lane = threadIdx.x & 63;
    const int j    = b * 4 + wave;

    // ---- tiny points cell: 4 lanes of wave 0 handle this block's 4 entries
    if (threadIdx.x < 4) {
        int pj = b * 4 + threadIdx.x;
        float p0 = cur[0], p1 = cur[1], p2 = goal[0], p3 = goal[1];
        const float4* Wp4 = (const float4*)Wp;   // row = one float4
        float4 wi = Wp4[pj];
        float4 wg = Wp4[2 * H + pj];
        float4 wo = Wp4[3 * H + pj];
        float gi = wi.x * p0 + wi.y * p1 + wi.z * p2 + wi.w * p3 + bp_i[pj] + bp_h[pj];
        float gg = wg.x * p0 + wg.y * p1 + wg.z * p2 + wg.w * p3 + bp_i[2 * H + pj] + bp_h[2 * H + pj];
        float go = wo.x * p0 + wo.y * p1 + wo.z * p2 + wo.w * p3 + bp_i[3 * H + pj] + bp_h[3 * H + pj];
        float c = sigmoidf_(gi) * tanhf(gg);
        fin[H + pj] = sigmoidf_(go) * tanhf(c);
    }
    if (b == 0 && threadIdx.x == 4) {
        out[0] = fcb[0];
        out[1] = fcb[1];
    }

    // ---- phase 1: map-cell GEMV rows (i, g, o) for hidden index j
    {
        const float4* x4 = (const float4*)x;
        const float4* Wi = (const float4*)(Wm + (size_t)j * D2);
        const float4* Wg = (const float4*)(Wm + (size_t)(2 * H + j) * D2);
        const float4* Wo = (const float4*)(Wm + (size_t)(3 * H + j) * D2);
        float si = 0.f, sg = 0.f, so = 0.f;
#pragma unroll
        for (int it = 0; it < 8; ++it) {
            int idx = it * 64 + lane;      // 512 float4 per row
            float4 xv = x4[idx];
            float4 a = Wi[idx];
            si += a.x * xv.x + a.y * xv.y + a.z * xv.z + a.w * xv.w;
            float4 g = Wg[idx];
            sg += g.x * xv.x + g.y * xv.y + g.z * xv.z + g.w * xv.w;
            float4 o = Wo[idx];
            so += o.x * xv.x + o.y * xv.y + o.z * xv.z + o.w * xv.w;
        }
        si = wave_sum(si);
        sg = wave_sum(sg);
        so = wave_sum(so);
        if (lane == 0) {
            float gi = si + bm_i[j] + bm_h[j];
            float gg = sg + bm_i[2 * H + j] + bm_h[2 * H + j];
            float go = so + bm_i[3 * H + j] + bm_h[3 * H + j];
            float c = sigmoidf_(gi) * tanhf(gg);
            fin[j] = sigmoidf_(go) * tanhf(c);    // h_map[j]
        }
    }

    // ---- prefetch W_ih_1 rows for hidden index j into registers (fin-independent)
    float4 rA[8], rG[8], rO[8];
    {
        const float4* Vi = (const float4*)(W1 + (size_t)j * D2);
        const float4* Vg = (const float4*)(W1 + (size_t)(2 * H + j) * D2);
        const float4* Vo = (const float4*)(W1 + (size_t)(3 * H + j) * D2);
#pragma unroll
        for (int it = 0; it < 8; ++it) {
            int idx = it * 64 + lane;
            rA[it] = Vi[idx];
            rG[it] = Vg[idx];
            rO[it] = Vo[idx];
        }
    }
    float fw0 = fcw[j], fw1 = fcw[H + j];
    float bbi = b1_i[j] + b1_h[j];
    float bbg = b1_i[2 * H + j] + b1_h[2 * H + j];
    float bbo = b1_i[3 * H + j] + b1_h[3 * H + j];

    cg::this_grid().sync();

    // ---- phase 2: lstm1 GEMV vs register weights, then fused fc
    const float4* f4 = (const float4*)fin;
    float ti = 0.f, tg = 0.f, to = 0.f;
#pragma unroll
    for (int it = 0; it < 8; ++it) {
        int idx = it * 64 + lane;
        float4 xv = f4[idx];
        ti += rA[it].x * xv.x + rA[it].y * xv.y + rA[it].z * xv.z + rA[it].w * xv.w;
        tg += rG[it].x * xv.x + rG[it].y * xv.y + rG[it].z * xv.z + rG[it].w * xv.w;
        to += rO[it].x * xv.x + rO[it].y * xv.y + rO[it].z * xv.z + rO[it].w * xv.w;
    }
    ti = wave_sum(ti);
    tg = wave_sum(tg);
    to = wave_sum(to);

    __shared__ float s0[4], s1[4];
    if (lane == 0) {
        float gi = ti + bbi;
        float gg = tg + bbg;
        float go = to + bbo;
        float c = sigmoidf_(gi) * tanhf(gg);
        float h = sigmoidf_(go) * tanhf(c);       // h1[j]
        s0[wave] = h * fw0;
        s1[wave] = h * fw1;
    }
    __syncthreads();
    if (threadIdx.x == 0) {
        atomicAdd(&out[0], s0[0] + s0[1] + s0[2] + s0[3]);
        atomicAdd(&out[1], s1[0] + s1[1] + s1[2] + s1[3]);
    }
}

extern "C" void kernel_launch(void* const* d_in, const int* in_sizes, int n_in,
                              void* d_out, int out_size, void* d_ws, size_t ws_size,
                              hipStream_t stream) {
    const float* goal     = (const float*)d_in[0];
    const float* cur      = (const float*)d_in[1];
    const float* map      = (const float*)d_in[2];
    const float* W_ih_map = (const float*)d_in[3];
    // d_in[4] = W_hh_map  (unused: h0 = 0)
    const float* b_ih_map = (const float*)d_in[5];
    const float* b_hh_map = (const float*)d_in[6];
    const float* W_ih_pts = (const float*)d_in[7];
    // d_in[8] = W_hh_pts  (unused)
    const float* b_ih_pts = (const float*)d_in[9];
    const float* b_hh_pts = (const float*)d_in[10];
    const float* W_ih_1   = (const float*)d_in[11];
    // d_in[12] = W_hh_1   (unused)
    const float* b_ih_1   = (const float*)d_in[13];
    const float* b_hh_1   = (const float*)d_in[14];
    const float* fc_w     = (const float*)d_in[15];
    const float* fc_b     = (const float*)d_in[16];

    float* fin = (float*)d_ws;       // 2048 floats
    float* out = (float*)d_out;      // 2 floats

    void* args[] = {
        (void*)&map, (void*)&W_ih_map, (void*)&b_ih_map, (void*)&b_hh_map,
        (void*)&W_ih_pts, (void*)&b_ih_pts, (void*)&b_hh_pts,
        (void*)&W_ih_1, (void*)&b_ih_1, (void*)&b_hh_1,
        (void*)&goal, (void*)&cur, (void*)&fc_w, (void*)&fc_b,
        (void*)&fin, (void*)&out
    };
    hipLaunchCooperativeKernel((const void*)k_fused, dim3(256), dim3(256),
                               args, 0, stream);
}

// Round 3
// 29.338 us; speedup vs baseline: 2.1437x; 2.1437x over previous
//
#include <hip/hip_runtime.h>
#include <math.h>

#define H    1024
#define D2   2048   // input width of both big GEMVs

__device__ __forceinline__ float sigmoidf_(float x) {
    return 1.0f / (1.0f + expf(-x));
}

__device__ __forceinline__ float wave_sum(float v) {
#pragma unroll
    for (int off = 32; off >= 1; off >>= 1)
        v += __shfl_xor(v, off, 64);
    return v;
}

// Kernel A: 512 blocks x 256 threads. Block b owns hidden rows j = 2b, 2b+1
// of the map cell. Wave w: jl = w>>1, half = w&1 — computes the half-K
// (1024-wide) slice of gate rows (i,g,o) for j. LDS combines the two halves.
// Also: 2 lanes do the trivial points-cell rows, block 0 inits out = fc_b.
__global__ __launch_bounds__(256) void k_cellA(
    const float* __restrict__ x,      // map [2048]
    const float* __restrict__ Wm,     // W_ih_map [4096][2048]
    const float* __restrict__ bm_i,
    const float* __restrict__ bm_h,
    const float* __restrict__ Wp,     // W_ih_pts [4096][4]
    const float* __restrict__ bp_i,
    const float* __restrict__ bp_h,
    const float* __restrict__ goal,   // [2]
    const float* __restrict__ cur,    // [2]
    const float* __restrict__ fcb,    // [2]
    float* __restrict__ fin,          // ws: [0..1023]=h_map, [1024..2047]=h_pts
    float* __restrict__ out)          // [2]
{
    const int tid  = threadIdx.x;
    const int wave = tid >> 6;
    const int lane = tid & 63;
    const int jl   = wave >> 1;       // 0..1
    const int half = wave & 1;        // 0..1
    const int j    = blockIdx.x * 2 + jl;

    __shared__ float part[2][2][3];   // [jl][half][gate]

    // trivial points cell: lanes handle pj = 2b, 2b+1
    if (tid < 2) {
        int pj = blockIdx.x * 2 + tid;
        float p0 = cur[0], p1 = cur[1], p2 = goal[0], p3 = goal[1];
        const float4* Wp4 = (const float4*)Wp;   // one float4 per row
        float4 wi = Wp4[pj];
        float4 wg = Wp4[2 * H + pj];
        float4 wo = Wp4[3 * H + pj];
        float gi = wi.x * p0 + wi.y * p1 + wi.z * p2 + wi.w * p3 + bp_i[pj] + bp_h[pj];
        float gg = wg.x * p0 + wg.y * p1 + wg.z * p2 + wg.w * p3 + bp_i[2 * H + pj] + bp_h[2 * H + pj];
        float go = wo.x * p0 + wo.y * p1 + wo.z * p2 + wo.w * p3 + bp_i[3 * H + pj] + bp_h[3 * H + pj];
        float c = sigmoidf_(gi) * tanhf(gg);
        fin[H + pj] = sigmoidf_(go) * tanhf(c);
    }
    if (blockIdx.x == 0 && tid == 2) {
        out[0] = fcb[0];
        out[1] = fcb[1];
    }

    // half-K GEMV slice: 1024 floats = 256 float4, 4 per lane per gate
    {
        const float4* x4 = (const float4*)(x + half * 1024);
        const float4* Wi = (const float4*)(Wm + (size_t)j * D2 + half * 1024);
        const float4* Wg = (const float4*)(Wm + (size_t)(2 * H + j) * D2 + half * 1024);
        const float4* Wo = (const float4*)(Wm + (size_t)(3 * H + j) * D2 + half * 1024);
        float si = 0.f, sg = 0.f, so = 0.f;
#pragma unroll
        for (int it = 0; it < 4; ++it) {
            int idx = it * 64 + lane;
            float4 xv = x4[idx];
            float4 a = Wi[idx];
            si += a.x * xv.x + a.y * xv.y + a.z * xv.z + a.w * xv.w;
            float4 g = Wg[idx];
            sg += g.x * xv.x + g.y * xv.y + g.z * xv.z + g.w * xv.w;
            float4 o = Wo[idx];
            so += o.x * xv.x + o.y * xv.y + o.z * xv.z + o.w * xv.w;
        }
        si = wave_sum(si);
        sg = wave_sum(sg);
        so = wave_sum(so);
        if (lane == 0) {
            part[jl][half][0] = si;
            part[jl][half][1] = sg;
            part[jl][half][2] = so;
        }
    }
    __syncthreads();
    if (half == 0 && lane == 0) {     // tid == jl*128
        float gi = part[jl][0][0] + part[jl][1][0] + bm_i[j] + bm_h[j];
        float gg = part[jl][0][1] + part[jl][1][1] + bm_i[2 * H + j] + bm_h[2 * H + j];
        float go = part[jl][0][2] + part[jl][1][2] + bm_i[3 * H + j] + bm_h[3 * H + j];
        float c = sigmoidf_(gi) * tanhf(gg);
        fin[j] = sigmoidf_(go) * tanhf(c);       // h_map[j]
    }
}

// Kernel B: same decomposition for lstm1 on fin[2048], with the fc layer
// fused: per-block LDS reduce of h1_j * fc_w, then 2 atomicAdds into out.
__global__ __launch_bounds__(256) void k_cellB(
    const float* __restrict__ fin,    // ws [2048]
    const float* __restrict__ W1,     // W_ih_1 [4096][2048]
    const float* __restrict__ b1_i,
    const float* __restrict__ b1_h,
    const float* __restrict__ fcw,    // [2][1024]
    float* __restrict__ out)          // [2]
{
    const int tid  = threadIdx.x;
    const int wave = tid >> 6;
    const int lane = tid & 63;
    const int jl   = wave >> 1;
    const int half = wave & 1;
    const int j    = blockIdx.x * 2 + jl;

    __shared__ float part[2][2][3];
    __shared__ float hs[2][2];        // [jl][fc row]

    {
        const float4* x4 = (const float4*)(fin + half * 1024);
        const float4* Wi = (const float4*)(W1 + (size_t)j * D2 + half * 1024);
        const float4* Wg = (const float4*)(W1 + (size_t)(2 * H + j) * D2 + half * 1024);
        const float4* Wo = (const float4*)(W1 + (size_t)(3 * H + j) * D2 + half * 1024);
        float si = 0.f, sg = 0.f, so = 0.f;
#pragma unroll
        for (int it = 0; it < 4; ++it) {
            int idx = it * 64 + lane;
            float4 xv = x4[idx];
            float4 a = Wi[idx];
            si += a.x * xv.x + a.y * xv.y + a.z * xv.z + a.w * xv.w;
            float4 g = Wg[idx];
            sg += g.x * xv.x + g.y * xv.y + g.z * xv.z + g.w * xv.w;
            float4 o = Wo[idx];
            so += o.x * xv.x + o.y * xv.y + o.z * xv.z + o.w * xv.w;
        }
        si = wave_sum(si);
        sg = wave_sum(sg);
        so = wave_sum(so);
        if (lane == 0) {
            part[jl][half][0] = si;
            part[jl][half][1] = sg;
            part[jl][half][2] = so;
        }
    }
    __syncthreads();
    if (half == 0 && lane == 0) {
        float gi = part[jl][0][0] + part[jl][1][0] + b1_i[j] + b1_h[j];
        float gg = part[jl][0][1] + part[jl][1][1] + b1_i[2 * H + j] + b1_h[2 * H + j];
        float go = part[jl][0][2] + part[jl][1][2] + b1_i[3 * H + j] + b1_h[3 * H + j];
        float c = sigmoidf_(gi) * tanhf(gg);
        float h = sigmoidf_(go) * tanhf(c);      // h1[j]
        hs[jl][0] = h * fcw[j];
        hs[jl][1] = h * fcw[H + j];
    }
    __syncthreads();
    if (tid == 0) {
        atomicAdd(&out[0], hs[0][0] + hs[1][0]);
        atomicAdd(&out[1], hs[0][1] + hs[1][1]);
    }
}

extern "C" void kernel_launch(void* const* d_in, const int* in_sizes, int n_in,
                              void* d_out, int out_size, void* d_ws, size_t ws_size,
                              hipStream_t stream) {
    const float* goal     = (const float*)d_in[0];
    const float* cur      = (const float*)d_in[1];
    const float* map      = (const float*)d_in[2];
    const float* W_ih_map = (const float*)d_in[3];
    // d_in[4] = W_hh_map  (unused: h0 = 0)
    const float* b_ih_map = (const float*)d_in[5];
    const float* b_hh_map = (const float*)d_in[6];
    const float* W_ih_pts = (const float*)d_in[7];
    // d_in[8] = W_hh_pts  (unused)
    const float* b_ih_pts = (const float*)d_in[9];
    const float* b_hh_pts = (const float*)d_in[10];
    const float* W_ih_1   = (const float*)d_in[11];
    // d_in[12] = W_hh_1   (unused)
    const float* b_ih_1   = (const float*)d_in[13];
    const float* b_hh_1   = (const float*)d_in[14];
    const float* fc_w     = (const float*)d_in[15];
    const float* fc_b     = (const float*)d_in[16];

    float* fin = (float*)d_ws;       // 2048 floats
    float* out = (float*)d_out;      // 2 floats

    k_cellA<<<512, 256, 0, stream>>>(map, W_ih_map, b_ih_map, b_hh_map,
                                     W_ih_pts, b_ih_pts, b_hh_pts,
                                     goal, cur, fc_b, fin, out);
    k_cellB<<<512, 256, 0, stream>>>(fin, W_ih_1, b_ih_1, b_hh_1, fc_w, out);
}